// Round 1
// baseline (1652.052 us; speedup 1.0000x reference)
//
#include <hip/hip_runtime.h>
#include <math.h>

// Problem constants (from setup_inputs): B=256, H=W=64, D=256, E=8
constexpr int NB     = 256;            // batch
constexpr int NE     = 8;              // experts
constexpr long KTOT  = 4096L * 256L;   // HW*D = 1,048,576 (flattened length)
constexpr int BG     = 8;              // b's per block in k_dots
constexpr int BGROUPS = NB / BG;       // 32
constexpr int KSPLIT = 32;             // k chunks
constexpr long KCHUNK = KTOT / KSPLIT; // 32768
constexpr int ITERS  = (int)(KCHUNK / (256 * 4)); // 32 float4-iters per block

typedef float v4f __attribute__((ext_vector_type(4)));

// ---------------- Kernel 1: dots[b][e], ||x_b||^2, ||m_e||^2 ----------------
// x is single-use -> nontemporal loads keep mem's 32 MiB resident in L2/LLC
// so the 32x bgroup re-reads of mem stay cache-served instead of HBM.
__global__ __launch_bounds__(256) void k_dots(
    const float* __restrict__ x, const float* __restrict__ mem,
    float* __restrict__ dots, float* __restrict__ xnorm2,
    float* __restrict__ mnorm2)
{
    const int bgroup = blockIdx.x & (BGROUPS - 1); // same-kchunk blocks adjacent
    const int kchunk = blockIdx.x / BGROUPS;
    const int tid    = threadIdx.x;
    const int b0     = bgroup * BG;
    const long kbase = (long)kchunk * KCHUNK + (long)tid * 4;

    float acc[BG][NE];
    float xn[BG];
    float mn[NE];
#pragma unroll
    for (int b = 0; b < BG; ++b) {
        xn[b] = 0.f;
#pragma unroll
        for (int e = 0; e < NE; ++e) acc[b][e] = 0.f;
    }
#pragma unroll
    for (int e = 0; e < NE; ++e) mn[e] = 0.f;

    for (int it = 0; it < ITERS; ++it) {
        const long k = kbase + (long)it * 1024;
        v4f m4[NE];
#pragma unroll
        for (int e = 0; e < NE; ++e)
            m4[e] = *(const v4f*)(mem + (long)e * KTOT + k);   // cached (reused 32x)
        if (bgroup == 0) {
#pragma unroll
            for (int e = 0; e < NE; ++e)
                mn[e] += m4[e].x * m4[e].x + m4[e].y * m4[e].y +
                         m4[e].z * m4[e].z + m4[e].w * m4[e].w;
        }
#pragma unroll
        for (int b = 0; b < BG; ++b) {
            const v4f xv = __builtin_nontemporal_load(
                (const v4f*)(x + (long)(b0 + b) * KTOT + k));  // streamed (single-use)
            xn[b] += xv.x * xv.x + xv.y * xv.y + xv.z * xv.z + xv.w * xv.w;
#pragma unroll
            for (int e = 0; e < NE; ++e)
                acc[b][e] += xv.x * m4[e].x + xv.y * m4[e].y +
                             xv.z * m4[e].z + xv.w * m4[e].w;
        }
    }

    const int lane = tid & 63;
#pragma unroll
    for (int b = 0; b < BG; ++b) {
#pragma unroll
        for (int e = 0; e < NE; ++e) {
            float v = acc[b][e];
#pragma unroll
            for (int s = 32; s >= 1; s >>= 1) v += __shfl_down(v, s, 64);
            if (lane == 0) atomicAdd(&dots[(b0 + b) * NE + e], v);
        }
        float v = xn[b];
#pragma unroll
        for (int s = 32; s >= 1; s >>= 1) v += __shfl_down(v, s, 64);
        if (lane == 0) atomicAdd(&xnorm2[b0 + b], v);
    }
    if (bgroup == 0) {
#pragma unroll
        for (int e = 0; e < NE; ++e) {
            float v = mn[e];
#pragma unroll
            for (int s = 32; s >= 1; s >>= 1) v += __shfl_down(v, s, 64);
            if (lane == 0) atomicAdd(&mnorm2[e], v);
        }
    }
}

// ---------------- Kernel 2: argmax + expert grouping ----------------
__global__ __launch_bounds__(256) void k_argmax(
    const float* __restrict__ dots, const float* __restrict__ xnorm2,
    const float* __restrict__ mnorm2, float* __restrict__ out_experts,
    int* __restrict__ order, int* __restrict__ offsets)
{
    __shared__ int   cnt[NE];
    __shared__ int   cur[NE];
    __shared__ int   off[NE + 1];
    __shared__ float smn[NE];
    const int tid = threadIdx.x; // tid == b
    if (tid < NE) { cnt[tid] = 0; cur[tid] = 0; smn[tid] = sqrtf(mnorm2[tid]); }
    __syncthreads();

    const float xn = sqrtf(xnorm2[tid]);
    int best = 0;
    float bestv = -__builtin_inff();
#pragma unroll
    for (int e = 0; e < NE; ++e) {
        const float denom = fmaxf(xn * smn[e], 1e-8f);
        const float sim = dots[tid * NE + e] / denom;
        if (sim > bestv) { bestv = sim; best = e; } // strict > == first-max
    }
    out_experts[tid] = (float)best;
    atomicAdd(&cnt[best], 1);
    __syncthreads();
    if (tid == 0) {
        int s = 0;
        for (int e = 0; e < NE; ++e) { off[e] = s; s += cnt[e]; }
        off[NE] = s;
    }
    __syncthreads();
    const int pos = off[best] + atomicAdd(&cur[best], 1);
    order[pos] = tid;
    if (tid < NE + 1) offsets[tid] = off[tid];
}

// ---------------- Kernel 3: scatter-mean + memory update ----------------
// 32 B per thread (2 adjacent float4 accumulators): 2x the in-flight loads,
// half the loop overhead. x streamed nontemporal; outmem stored nontemporal.
__global__ __launch_bounds__(256) void k_scatter(
    const float* __restrict__ x, const float* __restrict__ mem,
    const int* __restrict__ order, const int* __restrict__ offsets,
    float* __restrict__ outmem)
{
    __shared__ int s_order[NB];
    __shared__ int s_off[NE + 1];
    const int tid = threadIdx.x;
    s_order[tid] = order[tid];
    if (tid < NE + 1) s_off[tid] = offsets[tid];
    __syncthreads();

    const long j = ((long)blockIdx.x * 256 + tid) * 8;
#pragma unroll 1
    for (int e = 0; e < NE; ++e) {
        const int beg = s_off[e], end = s_off[e + 1];
        v4f s0 = {0.f, 0.f, 0.f, 0.f};
        v4f s1 = {0.f, 0.f, 0.f, 0.f};
        for (int i = beg; i < end; ++i) {
            const int b = s_order[i];
            const float* p = x + (long)b * KTOT + j;
            s0 += __builtin_nontemporal_load((const v4f*)p);
            s1 += __builtin_nontemporal_load((const v4f*)(p + 4));
        }
        const v4f mv0 = *(const v4f*)(mem + (long)e * KTOT + j);
        const v4f mv1 = *(const v4f*)(mem + (long)e * KTOT + j + 4);
        const int n = end - beg;
        v4f o0, o1;
        if (n > 0) {
            const float inv = 1.0f / (float)n;
            o0 = (mv0 + s0 * inv) * 0.5f;
            o1 = (mv1 + s1 * inv) * 0.5f;
        } else {
            o0 = mv0;
            o1 = mv1;
        }
        __builtin_nontemporal_store(o0, (v4f*)(outmem + (long)e * KTOT + j));
        __builtin_nontemporal_store(o1, (v4f*)(outmem + (long)e * KTOT + j + 4));
    }
}

extern "C" void kernel_launch(void* const* d_in, const int* in_sizes, int n_in,
                              void* d_out, int out_size, void* d_ws, size_t ws_size,
                              hipStream_t stream)
{
    const float* x   = (const float*)d_in[0]; // [256, 64, 64, 256]
    const float* mem = (const float*)d_in[1]; // [8, 4096, 256]
    float* out = (float*)d_out;               // [256 experts][8*4096*256 new_memory]

    // Workspace layout
    float* dots   = (float*)d_ws;          // 256*8
    float* xnorm2 = dots + NB * NE;        // 256
    float* mnorm2 = xnorm2 + NB;           // 8
    int*   order  = (int*)(mnorm2 + NE);   // 256
    int*   offsets = order + NB;           // 9

    // zero the float accumulators (ws is re-poisoned to 0xAA every launch)
    hipMemsetAsync(d_ws, 0, (size_t)(NB * NE + NB + NE) * sizeof(float), stream);

    k_dots<<<BGROUPS * KSPLIT, 256, 0, stream>>>(x, mem, dots, xnorm2, mnorm2);
    k_argmax<<<1, 256, 0, stream>>>(dots, xnorm2, mnorm2, out, order, offsets);
    k_scatter<<<(int)(KTOT / (256 * 8)), 256, 0, stream>>>(x, mem, order, offsets,
                                                           out + NB);
}